// Round 12
// baseline (613.665 us; speedup 1.0000x reference)
//
#include <hip/hip_runtime.h>
#include <hip/hip_fp16.h>
#include <cstdint>
#include <cstddef>

#define HIDC   64
#define NGAUSS 50
#define NLAYER 3
#define TGRID  8192            // nearest-neighbor grid; d-err <= 6.1e-4; 1MB/layer fp16
#define BSTRIDE 128            // dst nodes per bucket
#define MAXBUCK 1024           // supports N <= 131072
#define CHUNK_E 6656           // edges per partition chunk (stage fits 64KB LDS)
#define CUTOFF_F 10.0f
#define LOG2_C 0.69314718055994530942f

typedef _Float16 f16x8 __attribute__((ext_vector_type(8)));
typedef float f32x4 __attribute__((ext_vector_type(4)));
#define MFMA16(a, b, c) __builtin_amdgcn_mfma_f32_16x16x32_f16(a, b, c, 0, 0, 0)

__device__ __forceinline__ float sspf(float v) {
  return fmaxf(v, 0.0f) + log1pf(expf(-fabsf(v))) - LOG2_C;
}

// ---------------------------------------------------------------------------
// Per-layer fp16 lookup tables T_l(g,j) = [ssp(rbf(d)@w1+b1)@w2+b2]_j * C(d)
// ---------------------------------------------------------------------------
__global__ __launch_bounds__(64) void build_table_k(
    const float* __restrict__ mlp_w1, const float* __restrict__ mlp_b1,
    const float* __restrict__ mlp_w2, const float* __restrict__ mlp_b2,
    __half* __restrict__ tabh) {
  int pid = blockIdx.x;              // l*TGRID + g
  int l = pid / TGRID;
  int g = pid - l * TGRID;
  int j = threadIdx.x;
  float d = (float)g * (CUTOFF_F / (float)(TGRID - 1));
  __shared__ float rbf_s[NGAUSS];
  __shared__ float hid_s[HIDC];
  const float delta = CUTOFF_F / (float)(NGAUSS - 1);
  const float coeff = -0.5f / (delta * delta);
  if (j < NGAUSS) {
    float t = d - (float)j * delta;
    rbf_s[j] = expf(coeff * t * t);
  }
  __syncthreads();
  const float* w1 = mlp_w1 + (size_t)l * NGAUSS * HIDC;
  float acc = mlp_b1[l * HIDC + j];
#pragma unroll
  for (int k = 0; k < NGAUSS; ++k) acc = fmaf(rbf_s[k], w1[k * HIDC + j], acc);
  hid_s[j] = sspf(acc);
  __syncthreads();
  const float* w2 = mlp_w2 + (size_t)l * HIDC * HIDC;
  float acc2 = mlp_b2[l * HIDC + j];
#pragma unroll
  for (int m = 0; m < HIDC; ++m) acc2 = fmaf(hid_s[m], w2[m * HIDC + j], acc2);
  float C = 0.5f * (cosf(d * (3.14159265358979323846f / CUTOFF_F)) + 1.0f);
  tabh[(size_t)pid * HIDC + j] = __float2half(acc2 * C);
}

// ---------------------------------------------------------------------------
// Pack fp32 row-major weights [64][nc] into fp16 MFMA B-fragment order:
// dst[((ct*2+kh)*64 + lane)*8 + j] = W[kh*32 + (lane>>4)*8 + j][ct*16 + (lane&15)]
// blockIdx: 0-2 cf1[l], 3-5 cf2[l], 6-8 intw[l], 9 ow1 (nc=32).
// ---------------------------------------------------------------------------
__global__ __launch_bounds__(64) void pack_all_k(
    const float* __restrict__ cf1, const float* __restrict__ cf2,
    const float* __restrict__ intw, const float* __restrict__ ow1,
    __half* __restrict__ wpk) {
  int m = blockIdx.x;
  int lane = threadIdx.x;
  const float* src;
  int nc = 64;
  if (m < 3)      src = cf1 + (size_t)m * 4096;
  else if (m < 6) src = cf2 + (size_t)(m - 3) * 4096;
  else if (m < 9) src = intw + (size_t)(m - 6) * 4096;
  else          { src = ow1; nc = 32; }
  __half* dst = wpk + (size_t)m * 4096;
  for (int ct = 0; ct < nc / 16; ++ct)
    for (int kh = 0; kh < 2; ++kh)
      for (int j = 0; j < 8; ++j)
        dst[((ct * 2 + kh) * 64 + lane) * 8 + j] =
            __float2half(src[(kh * 32 + (lane >> 4) * 8 + j) * nc +
                             ct * 16 + (lane & 15)]);
}

// ---------------------------------------------------------------------------
// Chunked partition. chist accumulates bcnt directly (R7: csum deleted).
// ---------------------------------------------------------------------------
__global__ __launch_bounds__(256) void chist_k(
    const int* __restrict__ edst, int* __restrict__ chunk_hist,
    int* __restrict__ bcnt, int E, int nbuck) {
  __shared__ int cnt[MAXBUCK];
  for (int i = threadIdx.x; i < MAXBUCK; i += 256) cnt[i] = 0;
  __syncthreads();
  int c = blockIdx.x;
  int e0 = c * CHUNK_E;
  int e1 = e0 + CHUNK_E; if (e1 > E) e1 = E;
  for (int e = e0 + threadIdx.x; e < e1; e += 256)
    atomicAdd(&cnt[edst[e] >> 7], 1);
  __syncthreads();
  for (int i = threadIdx.x; i < nbuck; i += 256) {
    int v = cnt[i];
    chunk_hist[c * MAXBUCK + i] = v;
    if (v) atomicAdd(&bcnt[i], v);
  }
}

__global__ __launch_bounds__(256) void bscan_k(
    const int* __restrict__ bcnt, int* __restrict__ boff, int nbuck) {
  __shared__ int sbuf[2][256];
  int tid = threadIdx.x;
  int base = tid * 4;
  int v0 = (base + 0 < nbuck) ? bcnt[base + 0] : 0;
  int v1 = (base + 1 < nbuck) ? bcnt[base + 1] : 0;
  int v2 = (base + 2 < nbuck) ? bcnt[base + 2] : 0;
  int v3 = (base + 3 < nbuck) ? bcnt[base + 3] : 0;
  int p0 = v0, p1 = p0 + v1, p2 = p1 + v2, p3 = p2 + v3;
  int pout = 0;
  sbuf[0][tid] = p3;
  __syncthreads();
  for (int off = 1; off < 256; off <<= 1) {
    int pin = pout; pout ^= 1;
    int v = sbuf[pin][tid];
    if (tid >= off) v += sbuf[pin][tid - off];
    sbuf[pout][tid] = v;
    __syncthreads();
  }
  int texc = sbuf[pout][tid] - p3;
  if (base + 0 < nbuck) boff[base + 0] = texc;
  if (base + 1 < nbuck) boff[base + 1] = texc + p0;
  if (base + 2 < nbuck) boff[base + 2] = texc + p1;
  if (base + 3 < nbuck) boff[base + 3] = texc + p2;
}

__global__ __launch_bounds__(256) void cbase_k(
    const int* __restrict__ chunk_hist, const int* __restrict__ boff,
    int* __restrict__ chunk_base, int nchunk) {
  __shared__ int sbuf[2][256];
  int b = blockIdx.x;
  int tid = threadIdx.x;
  int carry = 0;
  for (int t0 = 0; t0 < nchunk; t0 += 256) {
    int t = t0 + tid;
    int v = (t < nchunk) ? chunk_hist[(size_t)t * MAXBUCK + b] : 0;
    int pout = 0;
    sbuf[0][tid] = v;
    __syncthreads();
    for (int off = 1; off < 256; off <<= 1) {
      int pin = pout; pout ^= 1;
      int s = sbuf[pin][tid];
      if (tid >= off) s += sbuf[pin][tid - off];
      sbuf[pout][tid] = s;
      __syncthreads();
    }
    if (t < nchunk)
      chunk_base[(size_t)t * MAXBUCK + b] = boff[b] + carry + sbuf[pout][tid] - v;
    carry += sbuf[pout][255];
    __syncthreads();
  }
}

// LDS-staged scatter. 512 threads (8 waves); prefix-scan scratch reuses
// stage_a so LDS stays 60KB.
__global__ __launch_bounds__(512) void cstage_k(
    const int* __restrict__ ei, const float* __restrict__ pos,
    const int* __restrict__ chunk_hist, const int* __restrict__ chunk_base,
    int2* __restrict__ er, int E, int nbuck) {
  __shared__ int stage_a[CHUNK_E];    // 26624 B (first 4KB doubles as scan scratch)
  __shared__ int stage_b[CHUNK_E];    // 26624 B
  __shared__ int loff[MAXBUCK];       // 4096 B
  __shared__ int lcur[MAXBUCK];       // 4096 B  (total 61440 B)
  int c = blockIdx.x;
  int tid = threadIdx.x;              // 0..511
  const int* hrow = chunk_hist + (size_t)c * MAXBUCK;
  int b0 = tid * 2;
  int v0 = (b0     < nbuck) ? hrow[b0]     : 0;
  int v1 = (b0 + 1 < nbuck) ? hrow[b0 + 1] : 0;
  int p1 = v0 + v1;
  int (*sb)[512] = (int (*)[512])stage_a;
  int pout = 0;
  sb[0][tid] = p1;
  __syncthreads();
  for (int off = 1; off < 512; off <<= 1) {
    int pin = pout; pout ^= 1;
    int v = sb[pin][tid];
    if (tid >= off) v += sb[pin][tid - off];
    sb[pout][tid] = v;
    __syncthreads();
  }
  int texc = sb[pout][tid] - p1;
  loff[b0] = texc;          lcur[b0] = texc;
  loff[b0 + 1] = texc + v0; lcur[b0 + 1] = texc + v0;
  __syncthreads();
  int e0 = c * CHUNK_E;
  int e1 = e0 + CHUNK_E; if (e1 > E) e1 = E;
  for (int e = e0 + tid; e < e1; e += 512) {
    int s = ei[e], t = ei[E + e];
    float dx = pos[3 * s + 0] - pos[3 * t + 0];
    float dy = pos[3 * s + 1] - pos[3 * t + 1];
    float dz = pos[3 * s + 2] - pos[3 * t + 2];
    float d = sqrtf(fmaf(dx, dx, fmaf(dy, dy, dz * dz)));
    float u = d * ((float)(TGRID - 1) / CUTOFF_F);
    int i0 = (int)(u + 0.5f);          // nearest
    if (i0 > TGRID - 1) i0 = TGRID - 1;
    int b = t >> 7;
    int dl = t & 127;
    int p = atomicAdd(&lcur[b], 1);
    stage_a[p] = s | (dl << 20);
    stage_b[p] = i0 | (b << 13);       // i0 is 13 bits (TGRID=8192)
  }
  __syncthreads();
  int total = e1 - e0;
  for (int i = tid; i < total; i += 512) {
    int sbv = stage_b[i];
    int b = sbv >> 13;
    int gb = chunk_base[(size_t)c * MAXBUCK + b];
    er[gb + (i - loff[b])] = make_int2(stage_a[i], sbv & 0x1FFF);
  }
}

// One WG per bucket: self-computed node-CSR (degrees + scan -> rs), place.
// Final records packed to 4 B: src(17) | i0(15)<<17.
__global__ __launch_bounds__(256) void bsort_k(
    const int* __restrict__ boff, const int* __restrict__ bcnt,
    const int2* __restrict__ er, int* __restrict__ er2,
    int* __restrict__ rs, int n) {
  __shared__ int dcnt[BSTRIDE];
  __shared__ int lcur[BSTRIDE];
  __shared__ int sc[2][BSTRIDE];
  int b = blockIdx.x;
  int node0 = b << 7;
  int nn = n - node0; if (nn > BSTRIDE) nn = BSTRIDE;
  int tid = threadIdx.x;
  if (tid < BSTRIDE) dcnt[tid] = 0;
  __syncthreads();
  int base = boff[b];
  int cnt = bcnt[b];
  for (int r = tid; r < cnt; r += 256)
    atomicAdd(&dcnt[(unsigned)er[base + r].x >> 20], 1);
  __syncthreads();
  int pout = 0;
  if (tid < BSTRIDE) sc[0][tid] = dcnt[tid];
  __syncthreads();
  for (int off = 1; off < BSTRIDE; off <<= 1) {
    int pin = pout; pout ^= 1;
    if (tid < BSTRIDE) {
      int v = sc[pin][tid];
      if (tid >= off) v += sc[pin][tid - off];
      sc[pout][tid] = v;
    }
    __syncthreads();
  }
  if (tid < BSTRIDE) {
    int start = base + sc[pout][tid] - dcnt[tid];
    lcur[tid] = start;
    if (tid < nn) rs[node0 + tid] = start;
  }
  if (tid == 0 && b == gridDim.x - 1) rs[n] = base + cnt;
  __syncthreads();
  for (int r = tid; r < cnt; r += 256) {
    int2 rec = er[base + r];
    int dl = (unsigned)rec.x >> 20;
    int p = atomicAdd(&lcur[dl], 1);
    er2[p] = (rec.x & 0x1FFFF) | (rec.y << 17);
  }
}

// ---------------------------------------------------------------------------
// MFMA node GEMMs. A: lane = row lane&15, k (lane>>4)*8+j (+32 2nd frag).
// B: pre-packed f16x8 fragments in VGPRs. C/D: col=lane&15, row=(lane>>4)*4+reg.
// ---------------------------------------------------------------------------

#define LOADB_P(P, Wpk) \
  const f16x8* P##p = (const f16x8*)(Wpk); \
  const f16x8 P##00 = P##p[0 * 64 + lane], P##01 = P##p[1 * 64 + lane]; \
  const f16x8 P##10 = P##p[2 * 64 + lane], P##11 = P##p[3 * 64 + lane]; \
  const f16x8 P##20 = P##p[4 * 64 + lane], P##21 = P##p[5 * 64 + lane]; \
  const f16x8 P##30 = P##p[6 * 64 + lane], P##31 = P##p[7 * 64 + lane];

#define GEMM_PRO \
  const int lane = threadIdx.x & 63; \
  const int r = lane & 15, g = lane >> 4; \
  const int wid = __builtin_amdgcn_readfirstlane( \
      (int)((blockIdx.x * 256 + threadIdx.x) >> 6)); \
  const int nwv = (int)(gridDim.x << 2); \
  const f32x4 z4 = {0.f, 0.f, 0.f, 0.f};

#define MFMA8(P, a0, a1, c0, c1, c2, c3) \
  c0 = MFMA16(a0, P##00, z4); c0 = MFMA16(a1, P##01, c0); \
  c1 = MFMA16(a0, P##10, z4); c1 = MFMA16(a1, P##11, c1); \
  c2 = MFMA16(a0, P##20, z4); c2 = MFMA16(a1, P##21, c2); \
  c3 = MFMA16(a0, P##30, z4); c3 = MFMA16(a1, P##31, c3);

// h = emb[z]; x = fp16(h @ C1_layer0). A-frags built straight from emb rows.
__global__ __launch_bounds__(256, 2) void init_lin_k(
    const int* __restrict__ z, const float* __restrict__ emb,
    const __half* __restrict__ wpk, float* __restrict__ h,
    __half* __restrict__ h16, __half* __restrict__ x, int ntiles, int n) {
  GEMM_PRO
  LOADB_P(B, wpk)
  for (int t = wid; t < ntiles; t += nwv) {
    int node = t * 16 + r;
    int nodec = node < n ? node : n - 1;
    const int zi = z[nodec];
    const float4* ep = (const float4*)(emb + ((size_t)zi << 6));
    float4 ea = ep[g * 2], eb = ep[g * 2 + 1];
    float4 ec = ep[8 + g * 2], ed = ep[8 + g * 2 + 1];
    f16x8 a0, a1;
    a0[0] = (_Float16)ea.x; a0[1] = (_Float16)ea.y;
    a0[2] = (_Float16)ea.z; a0[3] = (_Float16)ea.w;
    a0[4] = (_Float16)eb.x; a0[5] = (_Float16)eb.y;
    a0[6] = (_Float16)eb.z; a0[7] = (_Float16)eb.w;
    a1[0] = (_Float16)ec.x; a1[1] = (_Float16)ec.y;
    a1[2] = (_Float16)ec.z; a1[3] = (_Float16)ec.w;
    a1[4] = (_Float16)ed.x; a1[5] = (_Float16)ed.y;
    a1[6] = (_Float16)ed.z; a1[7] = (_Float16)ed.w;
    if (node < n) {
      float4* hp = (float4*)(h + ((size_t)node << 6) + g * 8);
      hp[0] = ea; hp[1] = eb;
      float4* hp2 = (float4*)(h + ((size_t)node << 6) + 32 + g * 8);
      hp2[0] = ec; hp2[1] = ed;
      *(f16x8*)(h16 + ((size_t)node << 6) + g * 8) = a0;
      *(f16x8*)(h16 + ((size_t)node << 6) + 32 + g * 8) = a1;
    }
    f32x4 c0, c1, c2, c3;
    MFMA8(B, a0, a1, c0, c1, c2, c3)
    const int nb = t * 16 + (g << 2);
#pragma unroll
    for (int q = 0; q < 4; ++q) {
      const int nq = nb + q;
      if (nq < n) {
        __half* o = x + ((size_t)nq << 6) + r;
        o[0]  = __float2half(c0[q]);
        o[16] = __float2half(c1[q]);
        o[32] = __float2half(c2[q]);
        o[48] = __float2half(c3[q]);
      }
    }
  }
}

// Fused update (last layer): t=ssp(agg@W2+b2); h+=t@W3+b3.
// Chained MFMAs: C-layout -> A-layout handoff via per-wave LDS tile [16][72]
// fp16. No __syncthreads: tiles are wave-private.
__global__ __launch_bounds__(256, 2) void upd0_k(
    const __half* __restrict__ aggh, const __half* __restrict__ wpk2,
    const float* __restrict__ b2, const __half* __restrict__ wpk3,
    const float* __restrict__ b3, float* __restrict__ h,
    __half* __restrict__ h16, int ntiles, int n) {
  __shared__ _Float16 lt[4][16][72];   // 9216 B; one tile per wave
  GEMM_PRO
  const int wslot = threadIdx.x >> 6;
  _Float16 (*T)[72] = lt[wslot];
  LOADB_P(B2, wpk2)
  LOADB_P(B3, wpk3)
  const float q2a = b2[r], q2b = b2[16 + r], q2c = b2[32 + r], q2d = b2[48 + r];
  const float q3a = b3[r], q3b = b3[16 + r], q3c = b3[32 + r], q3d = b3[48 + r];
  for (int t = wid; t < ntiles; t += nwv) {
    int arow = t * 16 + r; if (arow >= n) arow = n - 1;
    const f16x8* Ap = (const f16x8*)(aggh + ((size_t)arow << 6));
    const f16x8 a0 = Ap[g], a1 = Ap[4 + g];
    f32x4 c0, c1, c2, c3;
    MFMA8(B2, a0, a1, c0, c1, c2, c3)
#pragma unroll
    for (int q = 0; q < 4; ++q) {
      T[g * 4 + q][r]      = (_Float16)sspf(c0[q] + q2a);
      T[g * 4 + q][16 + r] = (_Float16)sspf(c1[q] + q2b);
      T[g * 4 + q][32 + r] = (_Float16)sspf(c2[q] + q2c);
      T[g * 4 + q][48 + r] = (_Float16)sspf(c3[q] + q2d);
    }
    const f16x8 t0 = *(const f16x8*)&T[r][g * 8];
    const f16x8 t1 = *(const f16x8*)&T[r][32 + g * 8];
    MFMA8(B3, t0, t1, c0, c1, c2, c3)
    const int nb = t * 16 + (g << 2);
#pragma unroll
    for (int q = 0; q < 4; ++q) {
      const int nq = nb + q;
      if (nq < n) {
        const size_t idx = ((size_t)nq << 6) + r;
        float n0 = h[idx +  0] + c0[q] + q3a;
        float n1 = h[idx + 16] + c1[q] + q3b;
        float n2 = h[idx + 32] + c2[q] + q3c;
        float n3 = h[idx + 48] + c3[q] + q3d;
        h[idx +  0] = n0; h16[idx +  0] = __float2half(n0);
        h[idx + 16] = n1; h16[idx + 16] = __float2half(n1);
        h[idx + 32] = n2; h16[idx + 32] = __float2half(n2);
        h[idx + 48] = n3; h16[idx + 48] = __float2half(n3);
      }
    }
  }
}

// Fused update + next-layer lin: t=ssp(agg@W2+b2); h+=t@W3+b3; x=fp16(h@C1next).
__global__ __launch_bounds__(256, 2) void upd1_k(
    const __half* __restrict__ aggh, const __half* __restrict__ wpk2,
    const float* __restrict__ b2, const __half* __restrict__ wpk3,
    const float* __restrict__ b3, float* __restrict__ h,
    __half* __restrict__ h16, const __half* __restrict__ wpkC,
    __half* __restrict__ x, int ntiles, int n) {
  __shared__ _Float16 lt[4][16][72];
  GEMM_PRO
  const int wslot = threadIdx.x >> 6;
  _Float16 (*T)[72] = lt[wslot];
  LOADB_P(B2, wpk2)
  LOADB_P(B3, wpk3)
  LOADB_P(BC, wpkC)
  const float q2a = b2[r], q2b = b2[16 + r], q2c = b2[32 + r], q2d = b2[48 + r];
  const float q3a = b3[r], q3b = b3[16 + r], q3c = b3[32 + r], q3d = b3[48 + r];
  for (int t = wid; t < ntiles; t += nwv) {
    int arow = t * 16 + r; if (arow >= n) arow = n - 1;
    const f16x8* Ap = (const f16x8*)(aggh + ((size_t)arow << 6));
    const f16x8 a0 = Ap[g], a1 = Ap[4 + g];
    f32x4 c0, c1, c2, c3;
    MFMA8(B2, a0, a1, c0, c1, c2, c3)
#pragma unroll
    for (int q = 0; q < 4; ++q) {
      T[g * 4 + q][r]      = (_Float16)sspf(c0[q] + q2a);
      T[g * 4 + q][16 + r] = (_Float16)sspf(c1[q] + q2b);
      T[g * 4 + q][32 + r] = (_Float16)sspf(c2[q] + q2c);
      T[g * 4 + q][48 + r] = (_Float16)sspf(c3[q] + q2d);
    }
    const f16x8 t0 = *(const f16x8*)&T[r][g * 8];
    const f16x8 t1 = *(const f16x8*)&T[r][32 + g * 8];
    MFMA8(B3, t0, t1, c0, c1, c2, c3)
    const int nb = t * 16 + (g << 2);
#pragma unroll
    for (int q = 0; q < 4; ++q) {
      const int nq = nb + q;
      float n0 = 0.f, n1 = 0.f, n2 = 0.f, n3 = 0.f;
      if (nq < n) {
        const size_t idx = ((size_t)nq << 6) + r;
        n0 = h[idx +  0] + c0[q] + q3a;
        n1 = h[idx + 16] + c1[q] + q3b;
        n2 = h[idx + 32] + c2[q] + q3c;
        n3 = h[idx + 48] + c3[q] + q3d;
        h[idx +  0] = n0; h16[idx +  0] = __float2half(n0);
        h[idx + 16] = n1; h16[idx + 16] = __float2half(n1);
        h[idx + 32] = n2; h16[idx + 32] = __float2half(n2);
        h[idx + 48] = n3; h16[idx + 48] = __float2half(n3);
      }
      T[g * 4 + q][r]      = (_Float16)n0;
      T[g * 4 + q][16 + r] = (_Float16)n1;
      T[g * 4 + q][32 + r] = (_Float16)n2;
      T[g * 4 + q][48 + r] = (_Float16)n3;
    }
    const f16x8 h0 = *(const f16x8*)&T[r][g * 8];
    const f16x8 h1 = *(const f16x8*)&T[r][32 + g * 8];
    MFMA8(BC, h0, h1, c0, c1, c2, c3)
#pragma unroll
    for (int q = 0; q < 4; ++q) {
      const int nq = nb + q;
      if (nq < n) {
        __half* o = x + ((size_t)nq << 6) + r;
        o[0]  = __float2half(c0[q]);
        o[16] = __float2half(c1[q]);
        o[32] = __float2half(c2[q]);
        o[48] = __float2half(c3[q]);
      }
    }
  }
}

// molecule output: o = h16 @ ow1 (64->32, 4 MFMAs); per-node
// s = sum_m ssp(o_m+b1_m)*ow2_m + b2 via 16-lane shfl_xor reduce; one atomic.
__global__ __launch_bounds__(256, 4) void outm16_k(
    const __half* __restrict__ h16, const int* __restrict__ batch,
    const __half* __restrict__ wpk, const float* __restrict__ ob1,
    const float* __restrict__ ow2, const float* __restrict__ ob2,
    float* __restrict__ outg, int ntiles, int n) {
  GEMM_PRO
  const f16x8* Bp = (const f16x8*)(wpk);
  const f16x8 b00 = Bp[0 * 64 + lane], b01 = Bp[1 * 64 + lane];
  const f16x8 b10 = Bp[2 * 64 + lane], b11 = Bp[3 * 64 + lane];
  const float b1a = ob1[r], b1b = ob1[16 + r];
  const float w2a = ow2[r], w2b = ow2[16 + r];
  const float b2o = ob2[0];
  for (int t = wid; t < ntiles; t += nwv) {
    int arow = t * 16 + r; if (arow >= n) arow = n - 1;
    const f16x8* Ap = (const f16x8*)(h16 + ((size_t)arow << 6));
    const f16x8 a0 = Ap[g], a1 = Ap[4 + g];
    f32x4 c0 = MFMA16(a0, b00, z4); c0 = MFMA16(a1, b01, c0);
    f32x4 c1 = MFMA16(a0, b10, z4); c1 = MFMA16(a1, b11, c1);
    float v0 = sspf(c0[0] + b1a) * w2a + sspf(c1[0] + b1b) * w2b;
    float v1 = sspf(c0[1] + b1a) * w2a + sspf(c1[1] + b1b) * w2b;
    float v2 = sspf(c0[2] + b1a) * w2a + sspf(c1[2] + b1b) * w2b;
    float v3 = sspf(c0[3] + b1a) * w2a + sspf(c1[3] + b1b) * w2b;
#pragma unroll
    for (int off = 1; off < 16; off <<= 1) {
      v0 += __shfl_xor(v0, off);
      v1 += __shfl_xor(v1, off);
      v2 += __shfl_xor(v2, off);
      v3 += __shfl_xor(v3, off);
    }
    if (r == 0) {
      const int nb = t * 16 + (g << 2);
      if (nb + 0 < n) unsafeAtomicAdd(&outg[batch[nb + 0]], v0 + b2o);
      if (nb + 1 < n) unsafeAtomicAdd(&outg[batch[nb + 1]], v1 + b2o);
      if (nb + 2 < n) unsafeAtomicAdd(&outg[batch[nb + 2]], v2 + b2o);
      if (nb + 3 < n) unsafeAtomicAdd(&outg[batch[nb + 3]], v3 + b2o);
    }
  }
}

// THE HOT KERNEL. R12: 4 edge-slots x 16 lanes — lane j owns channels
// 4(j&15)..+3 of edge-slot j>>4. Row loads are uint2 (8 B/lane; 16 lanes =
// full 128-B row) so ONE VMEM instruction fetches 4 edges' rows (was 2 B/lane
// sub-dword, 1/8 of the coalescing sweet spot; kernel was issue-bound at 40%
// VALU, 2.5x above its 27us HBM floor). Clamped tail slots select-zero the
// table value. 2-stage shfl_xor(16/32) combines the 4 slot partials.
__global__ __launch_bounds__(256) void gather_k(
    const int* __restrict__ rs, const int* __restrict__ er,
    const __half* __restrict__ tabh, const __half* __restrict__ x,
    __half* __restrict__ aggh, int n) {
  const int lane = threadIdx.x & 63;
  const int sub = lane >> 4;          // edge slot 0..3
  const int ch = (lane & 15) << 2;    // channel base
  int node = (blockIdx.x * 256 + threadIdx.x) >> 6;
  if (node >= n) return;
  int beg = __builtin_amdgcn_readfirstlane(rs[node]);
  int end = __builtin_amdgcn_readfirstlane(rs[node + 1]);
  float a0 = 0.f, a1 = 0.f, a2 = 0.f, a3 = 0.f;
  for (int k = beg; k < end; k += 8) {
    const int k0 = k + sub;
    const int k1 = k0 + 4;
    const int e0 = er[k0 < end ? k0 : end - 1];
    const int e1 = er[k1 < end ? k1 : end - 1];
    uint2 t0 = *(const uint2*)(tabh + (((size_t)((unsigned)e0 >> 17)) << 6) + ch);
    uint2 x0 = *(const uint2*)(x    + (((size_t)(e0 & 0x1FFFF)) << 6) + ch);
    uint2 t1 = *(const uint2*)(tabh + (((size_t)((unsigned)e1 >> 17)) << 6) + ch);
    uint2 x1 = *(const uint2*)(x    + (((size_t)(e1 & 0x1FFFF)) << 6) + ch);
    if (k0 >= end) { t0.x = 0u; t0.y = 0u; }
    if (k1 >= end) { t1.x = 0u; t1.y = 0u; }
    float2 ta = __half22float2(*(__half2*)&t0.x);
    float2 tb = __half22float2(*(__half2*)&t0.y);
    float2 xa = __half22float2(*(__half2*)&x0.x);
    float2 xb = __half22float2(*(__half2*)&x0.y);
    a0 = fmaf(xa.x, ta.x, a0);
    a1 = fmaf(xa.y, ta.y, a1);
    a2 = fmaf(xb.x, tb.x, a2);
    a3 = fmaf(xb.y, tb.y, a3);
    float2 tc = __half22float2(*(__half2*)&t1.x);
    float2 td = __half22float2(*(__half2*)&t1.y);
    float2 xc = __half22float2(*(__half2*)&x1.x);
    float2 xd = __half22float2(*(__half2*)&x1.y);
    a0 = fmaf(xc.x, tc.x, a0);
    a1 = fmaf(xc.y, tc.y, a1);
    a2 = fmaf(xd.x, td.x, a2);
    a3 = fmaf(xd.y, td.y, a3);
  }
  // combine the 4 edge-slot partials (lanes j, j^16, j^32, j^48)
#pragma unroll
  for (int off = 16; off <= 32; off <<= 1) {
    a0 += __shfl_xor(a0, off);
    a1 += __shfl_xor(a1, off);
    a2 += __shfl_xor(a2, off);
    a3 += __shfl_xor(a3, off);
  }
  if (sub == 0) {
    __half2 h0 = __floats2half2_rn(a0, a1);
    __half2 h1 = __floats2half2_rn(a2, a3);
    uint2 out;
    out.x = *(unsigned*)&h0;
    out.y = *(unsigned*)&h1;
    *(uint2*)(aggh + ((size_t)node << 6) + ch) = out;
  }
}

__global__ __launch_bounds__(256) void final_k(
    const float* __restrict__ outg, const float* __restrict__ fw,
    const float* __restrict__ fb, float* __restrict__ out, int g) {
  int i = blockIdx.x * blockDim.x + threadIdx.x;
  if (i < g) out[i] = fmaf(outg[i], fw[0], fb[0]);
}

extern "C" void kernel_launch(void* const* d_in, const int* in_sizes, int n_in,
                              void* d_out, int out_size, void* d_ws, size_t ws_size,
                              hipStream_t stream) {
  const int*   z      = (const int*)d_in[0];
  const float* pos    = (const float*)d_in[1];
  const int*   batch  = (const int*)d_in[2];
  const int*   ei     = (const int*)d_in[3];
  const float* emb    = (const float*)d_in[4];
  const float* out_w1 = (const float*)d_in[5];
  const float* out_b1 = (const float*)d_in[6];
  const float* out_w2 = (const float*)d_in[7];
  const float* out_b2 = (const float*)d_in[8];
  const float* fin_w  = (const float*)d_in[9];
  const float* fin_b  = (const float*)d_in[10];
  const float* mlp_w1 = (const float*)d_in[11];
  const float* mlp_b1 = (const float*)d_in[12];
  const float* mlp_w2 = (const float*)d_in[13];
  const float* mlp_b2 = (const float*)d_in[14];
  const float* cf1    = (const float*)d_in[15];
  const float* cf2    = (const float*)d_in[16];
  const float* cf2b   = (const float*)d_in[17];
  const float* intw   = (const float*)d_in[18];
  const float* intb   = (const float*)d_in[19];

  const int N = in_sizes[0];
  const int E = in_sizes[3] / 2;
  const int G = out_size;
  const int NBUCK = (N + BSTRIDE - 1) / BSTRIDE;
  const int NCHUNK = (E + CHUNK_E - 1) / CHUNK_E;
  const int NTILES = (N + 15) / 16;
  const int GB = (NTILES + 3) / 4;     // 4 waves/block, 1 tile/wave

  char* wsb = (char*)d_ws;
  size_t off = 0;
  auto alloc = [&](size_t bytes) { char* p = wsb + off; off += (bytes + 255) & ~(size_t)255; return p; };
  float*   h     = (float*)alloc((size_t)N * HIDC * sizeof(float));
  __half*  h16   = (__half*)alloc((size_t)N * HIDC * sizeof(__half));
  __half*  x     = (__half*)alloc((size_t)N * HIDC * sizeof(__half));
  __half*  aggh  = (__half*)alloc((size_t)N * HIDC * sizeof(__half));
  __half*  tabh  = (__half*)alloc((size_t)NLAYER * TGRID * HIDC * sizeof(__half));
  __half*  wpk   = (__half*)alloc((size_t)10 * 4096 * sizeof(__half));
  int2*    er    = (int2*)alloc((size_t)E * sizeof(int2));   // bucket-ordered
  int*     er2   = (int*)alloc((size_t)E * sizeof(int));     // node-CSR, 4B packed
  int*     rs    = (int*)alloc((size_t)(N + 1) * sizeof(int));
  int*     bcnt  = (int*)alloc((size_t)MAXBUCK * sizeof(int));
  int*     boff  = (int*)alloc((size_t)MAXBUCK * sizeof(int));
  int*     chist = (int*)alloc((size_t)NCHUNK * MAXBUCK * sizeof(int));
  int*     cbase = (int*)alloc((size_t)NCHUNK * MAXBUCK * sizeof(int));
  float*   outg  = (float*)alloc((size_t)G * sizeof(float));

  build_table_k<<<dim3(NLAYER * TGRID), dim3(64), 0, stream>>>(
      mlp_w1, mlp_b1, mlp_w2, mlp_b2, tabh);
  pack_all_k<<<dim3(10), dim3(64), 0, stream>>>(cf1, cf2, intw, out_w1, wpk);
  (void)hipMemsetAsync(outg, 0, (size_t)G * sizeof(float), stream);
  (void)hipMemsetAsync(bcnt, 0, (size_t)MAXBUCK * sizeof(int), stream);
  chist_k<<<dim3(NCHUNK), dim3(256), 0, stream>>>(ei + E, chist, bcnt, E, NBUCK);
  bscan_k<<<dim3(1), dim3(256), 0, stream>>>(bcnt, boff, NBUCK);
  cbase_k<<<dim3(NBUCK), dim3(256), 0, stream>>>(chist, boff, cbase, NCHUNK);
  cstage_k<<<dim3(NCHUNK), dim3(512), 0, stream>>>(
      ei, pos, chist, cbase, er, E, NBUCK);
  bsort_k<<<dim3(NBUCK), dim3(256), 0, stream>>>(boff, bcnt, er, er2, rs, N);
  init_lin_k<<<dim3(GB), dim3(256), 0, stream>>>(
      z, emb, wpk, h, h16, x, NTILES, N);

  const int gather_blocks = (N + 3) / 4;   // one wave per node
  for (int l = 0; l < NLAYER; ++l) {
    gather_k<<<dim3(gather_blocks), dim3(256), 0, stream>>>(
        rs, er2, tabh + (size_t)l * TGRID * HIDC, x, aggh, N);
    if (l < NLAYER - 1) {
      upd1_k<<<dim3(GB), dim3(256), 0, stream>>>(
          aggh, wpk + (size_t)(3 + l) * 4096, cf2b + l * HIDC,
          wpk + (size_t)(6 + l) * 4096, intb + l * HIDC, h, h16,
          wpk + (size_t)(l + 1) * 4096, x, NTILES, N);
    } else {
      upd0_k<<<dim3(GB), dim3(256), 0, stream>>>(
          aggh, wpk + (size_t)(3 + l) * 4096, cf2b + l * HIDC,
          wpk + (size_t)(6 + l) * 4096, intb + l * HIDC, h, h16, NTILES, N);
    }
  }

  outm16_k<<<dim3(GB), dim3(256), 0, stream>>>(
      h16, batch, wpk + (size_t)9 * 4096, out_b1, out_w2, out_b2, outg, NTILES, N);
  final_k<<<dim3((G + 255) / 256), dim3(256), 0, stream>>>(
      outg, fin_w, fin_b, (float*)d_out, G);
}

// Round 13
// 544.633 us; speedup vs baseline: 1.1267x; 1.1267x over previous
//
#include <hip/hip_runtime.h>
#include <hip/hip_fp16.h>
#include <cstdint>
#include <cstddef>

#define HIDC   64
#define NGAUSS 50
#define NLAYER 3
#define TGRID  8192            // nearest-neighbor grid; d-err <= 6.1e-4; 1MB/layer fp16
#define BSTRIDE 128            // dst nodes per bucket
#define MAXBUCK 1024           // supports N <= 131072
#define CHUNK_E 6656           // edges per partition chunk (stage fits 64KB LDS)
#define CUTOFF_F 10.0f
#define LOG2_C 0.69314718055994530942f

typedef _Float16 f16x8 __attribute__((ext_vector_type(8)));
typedef float f32x4 __attribute__((ext_vector_type(4)));
#define MFMA16(a, b, c) __builtin_amdgcn_mfma_f32_16x16x32_f16(a, b, c, 0, 0, 0)

__device__ __forceinline__ float sspf(float v) {
  return fmaxf(v, 0.0f) + log1pf(expf(-fabsf(v))) - LOG2_C;
}

// ---------------------------------------------------------------------------
// Per-layer fp16 lookup tables T_l(g,j) = [ssp(rbf(d)@w1+b1)@w2+b2]_j * C(d)
// ---------------------------------------------------------------------------
__global__ __launch_bounds__(64) void build_table_k(
    const float* __restrict__ mlp_w1, const float* __restrict__ mlp_b1,
    const float* __restrict__ mlp_w2, const float* __restrict__ mlp_b2,
    __half* __restrict__ tabh) {
  int pid = blockIdx.x;              // l*TGRID + g
  int l = pid / TGRID;
  int g = pid - l * TGRID;
  int j = threadIdx.x;
  float d = (float)g * (CUTOFF_F / (float)(TGRID - 1));
  __shared__ float rbf_s[NGAUSS];
  __shared__ float hid_s[HIDC];
  const float delta = CUTOFF_F / (float)(NGAUSS - 1);
  const float coeff = -0.5f / (delta * delta);
  if (j < NGAUSS) {
    float t = d - (float)j * delta;
    rbf_s[j] = expf(coeff * t * t);
  }
  __syncthreads();
  const float* w1 = mlp_w1 + (size_t)l * NGAUSS * HIDC;
  float acc = mlp_b1[l * HIDC + j];
#pragma unroll
  for (int k = 0; k < NGAUSS; ++k) acc = fmaf(rbf_s[k], w1[k * HIDC + j], acc);
  hid_s[j] = sspf(acc);
  __syncthreads();
  const float* w2 = mlp_w2 + (size_t)l * HIDC * HIDC;
  float acc2 = mlp_b2[l * HIDC + j];
#pragma unroll
  for (int m = 0; m < HIDC; ++m) acc2 = fmaf(hid_s[m], w2[m * HIDC + j], acc2);
  float C = 0.5f * (cosf(d * (3.14159265358979323846f / CUTOFF_F)) + 1.0f);
  tabh[(size_t)pid * HIDC + j] = __float2half(acc2 * C);
}

// ---------------------------------------------------------------------------
// Pack fp32 row-major weights [64][nc] into fp16 MFMA B-fragment order:
// dst[((ct*2+kh)*64 + lane)*8 + j] = W[kh*32 + (lane>>4)*8 + j][ct*16 + (lane&15)]
// blockIdx: 0-2 cf1[l], 3-5 cf2[l], 6-8 intw[l], 9 ow1 (nc=32).
// ---------------------------------------------------------------------------
__global__ __launch_bounds__(64) void pack_all_k(
    const float* __restrict__ cf1, const float* __restrict__ cf2,
    const float* __restrict__ intw, const float* __restrict__ ow1,
    __half* __restrict__ wpk) {
  int m = blockIdx.x;
  int lane = threadIdx.x;
  const float* src;
  int nc = 64;
  if (m < 3)      src = cf1 + (size_t)m * 4096;
  else if (m < 6) src = cf2 + (size_t)(m - 3) * 4096;
  else if (m < 9) src = intw + (size_t)(m - 6) * 4096;
  else          { src = ow1; nc = 32; }
  __half* dst = wpk + (size_t)m * 4096;
  for (int ct = 0; ct < nc / 16; ++ct)
    for (int kh = 0; kh < 2; ++kh)
      for (int j = 0; j < 8; ++j)
        dst[((ct * 2 + kh) * 64 + lane) * 8 + j] =
            __float2half(src[(kh * 32 + (lane >> 4) * 8 + j) * nc +
                             ct * 16 + (lane & 15)]);
}

// ---------------------------------------------------------------------------
// Chunked partition. chist accumulates bcnt directly (R7: csum deleted).
// ---------------------------------------------------------------------------
__global__ __launch_bounds__(256) void chist_k(
    const int* __restrict__ edst, int* __restrict__ chunk_hist,
    int* __restrict__ bcnt, int E, int nbuck) {
  __shared__ int cnt[MAXBUCK];
  for (int i = threadIdx.x; i < MAXBUCK; i += 256) cnt[i] = 0;
  __syncthreads();
  int c = blockIdx.x;
  int e0 = c * CHUNK_E;
  int e1 = e0 + CHUNK_E; if (e1 > E) e1 = E;
  for (int e = e0 + threadIdx.x; e < e1; e += 256)
    atomicAdd(&cnt[edst[e] >> 7], 1);
  __syncthreads();
  for (int i = threadIdx.x; i < nbuck; i += 256) {
    int v = cnt[i];
    chunk_hist[c * MAXBUCK + i] = v;
    if (v) atomicAdd(&bcnt[i], v);
  }
}

__global__ __launch_bounds__(256) void bscan_k(
    const int* __restrict__ bcnt, int* __restrict__ boff, int nbuck) {
  __shared__ int sbuf[2][256];
  int tid = threadIdx.x;
  int base = tid * 4;
  int v0 = (base + 0 < nbuck) ? bcnt[base + 0] : 0;
  int v1 = (base + 1 < nbuck) ? bcnt[base + 1] : 0;
  int v2 = (base + 2 < nbuck) ? bcnt[base + 2] : 0;
  int v3 = (base + 3 < nbuck) ? bcnt[base + 3] : 0;
  int p0 = v0, p1 = p0 + v1, p2 = p1 + v2, p3 = p2 + v3;
  int pout = 0;
  sbuf[0][tid] = p3;
  __syncthreads();
  for (int off = 1; off < 256; off <<= 1) {
    int pin = pout; pout ^= 1;
    int v = sbuf[pin][tid];
    if (tid >= off) v += sbuf[pin][tid - off];
    sbuf[pout][tid] = v;
    __syncthreads();
  }
  int texc = sbuf[pout][tid] - p3;
  if (base + 0 < nbuck) boff[base + 0] = texc;
  if (base + 1 < nbuck) boff[base + 1] = texc + p0;
  if (base + 2 < nbuck) boff[base + 2] = texc + p1;
  if (base + 3 < nbuck) boff[base + 3] = texc + p2;
}

__global__ __launch_bounds__(256) void cbase_k(
    const int* __restrict__ chunk_hist, const int* __restrict__ boff,
    int* __restrict__ chunk_base, int nchunk) {
  __shared__ int sbuf[2][256];
  int b = blockIdx.x;
  int tid = threadIdx.x;
  int carry = 0;
  for (int t0 = 0; t0 < nchunk; t0 += 256) {
    int t = t0 + tid;
    int v = (t < nchunk) ? chunk_hist[(size_t)t * MAXBUCK + b] : 0;
    int pout = 0;
    sbuf[0][tid] = v;
    __syncthreads();
    for (int off = 1; off < 256; off <<= 1) {
      int pin = pout; pout ^= 1;
      int s = sbuf[pin][tid];
      if (tid >= off) s += sbuf[pin][tid - off];
      sbuf[pout][tid] = s;
      __syncthreads();
    }
    if (t < nchunk)
      chunk_base[(size_t)t * MAXBUCK + b] = boff[b] + carry + sbuf[pout][tid] - v;
    carry += sbuf[pout][255];
    __syncthreads();
  }
}

// LDS-staged scatter. 512 threads (8 waves); prefix-scan scratch reuses
// stage_a so LDS stays 60KB.
__global__ __launch_bounds__(512) void cstage_k(
    const int* __restrict__ ei, const float* __restrict__ pos,
    const int* __restrict__ chunk_hist, const int* __restrict__ chunk_base,
    int2* __restrict__ er, int E, int nbuck) {
  __shared__ int stage_a[CHUNK_E];    // 26624 B (first 4KB doubles as scan scratch)
  __shared__ int stage_b[CHUNK_E];    // 26624 B
  __shared__ int loff[MAXBUCK];       // 4096 B
  __shared__ int lcur[MAXBUCK];       // 4096 B  (total 61440 B)
  int c = blockIdx.x;
  int tid = threadIdx.x;              // 0..511
  const int* hrow = chunk_hist + (size_t)c * MAXBUCK;
  int b0 = tid * 2;
  int v0 = (b0     < nbuck) ? hrow[b0]     : 0;
  int v1 = (b0 + 1 < nbuck) ? hrow[b0 + 1] : 0;
  int p1 = v0 + v1;
  int (*sb)[512] = (int (*)[512])stage_a;
  int pout = 0;
  sb[0][tid] = p1;
  __syncthreads();
  for (int off = 1; off < 512; off <<= 1) {
    int pin = pout; pout ^= 1;
    int v = sb[pin][tid];
    if (tid >= off) v += sb[pin][tid - off];
    sb[pout][tid] = v;
    __syncthreads();
  }
  int texc = sb[pout][tid] - p1;
  loff[b0] = texc;          lcur[b0] = texc;
  loff[b0 + 1] = texc + v0; lcur[b0 + 1] = texc + v0;
  __syncthreads();
  int e0 = c * CHUNK_E;
  int e1 = e0 + CHUNK_E; if (e1 > E) e1 = E;
  for (int e = e0 + tid; e < e1; e += 512) {
    int s = ei[e], t = ei[E + e];
    float dx = pos[3 * s + 0] - pos[3 * t + 0];
    float dy = pos[3 * s + 1] - pos[3 * t + 1];
    float dz = pos[3 * s + 2] - pos[3 * t + 2];
    float d = sqrtf(fmaf(dx, dx, fmaf(dy, dy, dz * dz)));
    float u = d * ((float)(TGRID - 1) / CUTOFF_F);
    int i0 = (int)(u + 0.5f);          // nearest
    if (i0 > TGRID - 1) i0 = TGRID - 1;
    int b = t >> 7;
    int dl = t & 127;
    int p = atomicAdd(&lcur[b], 1);
    stage_a[p] = s | (dl << 20);
    stage_b[p] = i0 | (b << 13);       // i0 is 13 bits (TGRID=8192)
  }
  __syncthreads();
  int total = e1 - e0;
  for (int i = tid; i < total; i += 512) {
    int sbv = stage_b[i];
    int b = sbv >> 13;
    int gb = chunk_base[(size_t)c * MAXBUCK + b];
    er[gb + (i - loff[b])] = make_int2(stage_a[i], sbv & 0x1FFF);
  }
}

// One WG per bucket: self-computed node-CSR (degrees + scan -> rs), place.
// Final records packed to 4 B: src(17) | i0(15)<<17.
__global__ __launch_bounds__(256) void bsort_k(
    const int* __restrict__ boff, const int* __restrict__ bcnt,
    const int2* __restrict__ er, int* __restrict__ er2,
    int* __restrict__ rs, int n) {
  __shared__ int dcnt[BSTRIDE];
  __shared__ int lcur[BSTRIDE];
  __shared__ int sc[2][BSTRIDE];
  int b = blockIdx.x;
  int node0 = b << 7;
  int nn = n - node0; if (nn > BSTRIDE) nn = BSTRIDE;
  int tid = threadIdx.x;
  if (tid < BSTRIDE) dcnt[tid] = 0;
  __syncthreads();
  int base = boff[b];
  int cnt = bcnt[b];
  for (int r = tid; r < cnt; r += 256)
    atomicAdd(&dcnt[(unsigned)er[base + r].x >> 20], 1);
  __syncthreads();
  int pout = 0;
  if (tid < BSTRIDE) sc[0][tid] = dcnt[tid];
  __syncthreads();
  for (int off = 1; off < BSTRIDE; off <<= 1) {
    int pin = pout; pout ^= 1;
    if (tid < BSTRIDE) {
      int v = sc[pin][tid];
      if (tid >= off) v += sc[pin][tid - off];
      sc[pout][tid] = v;
    }
    __syncthreads();
  }
  if (tid < BSTRIDE) {
    int start = base + sc[pout][tid] - dcnt[tid];
    lcur[tid] = start;
    if (tid < nn) rs[node0 + tid] = start;
  }
  if (tid == 0 && b == gridDim.x - 1) rs[n] = base + cnt;
  __syncthreads();
  for (int r = tid; r < cnt; r += 256) {
    int2 rec = er[base + r];
    int dl = (unsigned)rec.x >> 20;
    int p = atomicAdd(&lcur[dl], 1);
    er2[p] = (rec.x & 0x1FFFF) | (rec.y << 17);
  }
}

// ---------------------------------------------------------------------------
// MFMA node GEMMs. A: lane = row lane&15, k (lane>>4)*8+j (+32 2nd frag).
// B: pre-packed f16x8 fragments in VGPRs. C/D: col=lane&15, row=(lane>>4)*4+reg.
// ---------------------------------------------------------------------------

#define LOADB_P(P, Wpk) \
  const f16x8* P##p = (const f16x8*)(Wpk); \
  const f16x8 P##00 = P##p[0 * 64 + lane], P##01 = P##p[1 * 64 + lane]; \
  const f16x8 P##10 = P##p[2 * 64 + lane], P##11 = P##p[3 * 64 + lane]; \
  const f16x8 P##20 = P##p[4 * 64 + lane], P##21 = P##p[5 * 64 + lane]; \
  const f16x8 P##30 = P##p[6 * 64 + lane], P##31 = P##p[7 * 64 + lane];

#define GEMM_PRO \
  const int lane = threadIdx.x & 63; \
  const int r = lane & 15, g = lane >> 4; \
  const int wid = __builtin_amdgcn_readfirstlane( \
      (int)((blockIdx.x * 256 + threadIdx.x) >> 6)); \
  const int nwv = (int)(gridDim.x << 2); \
  const f32x4 z4 = {0.f, 0.f, 0.f, 0.f};

#define MFMA8(P, a0, a1, c0, c1, c2, c3) \
  c0 = MFMA16(a0, P##00, z4); c0 = MFMA16(a1, P##01, c0); \
  c1 = MFMA16(a0, P##10, z4); c1 = MFMA16(a1, P##11, c1); \
  c2 = MFMA16(a0, P##20, z4); c2 = MFMA16(a1, P##21, c2); \
  c3 = MFMA16(a0, P##30, z4); c3 = MFMA16(a1, P##31, c3);

// h = emb[z]; x = fp16(h @ C1_layer0). A-frags built straight from emb rows.
__global__ __launch_bounds__(256, 2) void init_lin_k(
    const int* __restrict__ z, const float* __restrict__ emb,
    const __half* __restrict__ wpk, float* __restrict__ h,
    __half* __restrict__ h16, __half* __restrict__ x, int ntiles, int n) {
  GEMM_PRO
  LOADB_P(B, wpk)
  for (int t = wid; t < ntiles; t += nwv) {
    int node = t * 16 + r;
    int nodec = node < n ? node : n - 1;
    const int zi = z[nodec];
    const float4* ep = (const float4*)(emb + ((size_t)zi << 6));
    float4 ea = ep[g * 2], eb = ep[g * 2 + 1];
    float4 ec = ep[8 + g * 2], ed = ep[8 + g * 2 + 1];
    f16x8 a0, a1;
    a0[0] = (_Float16)ea.x; a0[1] = (_Float16)ea.y;
    a0[2] = (_Float16)ea.z; a0[3] = (_Float16)ea.w;
    a0[4] = (_Float16)eb.x; a0[5] = (_Float16)eb.y;
    a0[6] = (_Float16)eb.z; a0[7] = (_Float16)eb.w;
    a1[0] = (_Float16)ec.x; a1[1] = (_Float16)ec.y;
    a1[2] = (_Float16)ec.z; a1[3] = (_Float16)ec.w;
    a1[4] = (_Float16)ed.x; a1[5] = (_Float16)ed.y;
    a1[6] = (_Float16)ed.z; a1[7] = (_Float16)ed.w;
    if (node < n) {
      float4* hp = (float4*)(h + ((size_t)node << 6) + g * 8);
      hp[0] = ea; hp[1] = eb;
      float4* hp2 = (float4*)(h + ((size_t)node << 6) + 32 + g * 8);
      hp2[0] = ec; hp2[1] = ed;
      *(f16x8*)(h16 + ((size_t)node << 6) + g * 8) = a0;
      *(f16x8*)(h16 + ((size_t)node << 6) + 32 + g * 8) = a1;
    }
    f32x4 c0, c1, c2, c3;
    MFMA8(B, a0, a1, c0, c1, c2, c3)
    const int nb = t * 16 + (g << 2);
#pragma unroll
    for (int q = 0; q < 4; ++q) {
      const int nq = nb + q;
      if (nq < n) {
        __half* o = x + ((size_t)nq << 6) + r;
        o[0]  = __float2half(c0[q]);
        o[16] = __float2half(c1[q]);
        o[32] = __float2half(c2[q]);
        o[48] = __float2half(c3[q]);
      }
    }
  }
}

// Fused update (last layer): t=ssp(agg@W2+b2); h+=t@W3+b3.
// Chained MFMAs: C-layout -> A-layout handoff via per-wave LDS tile [16][72]
// fp16. No __syncthreads: tiles are wave-private.
__global__ __launch_bounds__(256, 2) void upd0_k(
    const __half* __restrict__ aggh, const __half* __restrict__ wpk2,
    const float* __restrict__ b2, const __half* __restrict__ wpk3,
    const float* __restrict__ b3, float* __restrict__ h,
    __half* __restrict__ h16, int ntiles, int n) {
  __shared__ _Float16 lt[4][16][72];   // 9216 B; one tile per wave
  GEMM_PRO
  const int wslot = threadIdx.x >> 6;
  _Float16 (*T)[72] = lt[wslot];
  LOADB_P(B2, wpk2)
  LOADB_P(B3, wpk3)
  const float q2a = b2[r], q2b = b2[16 + r], q2c = b2[32 + r], q2d = b2[48 + r];
  const float q3a = b3[r], q3b = b3[16 + r], q3c = b3[32 + r], q3d = b3[48 + r];
  for (int t = wid; t < ntiles; t += nwv) {
    int arow = t * 16 + r; if (arow >= n) arow = n - 1;
    const f16x8* Ap = (const f16x8*)(aggh + ((size_t)arow << 6));
    const f16x8 a0 = Ap[g], a1 = Ap[4 + g];
    f32x4 c0, c1, c2, c3;
    MFMA8(B2, a0, a1, c0, c1, c2, c3)
#pragma unroll
    for (int q = 0; q < 4; ++q) {
      T[g * 4 + q][r]      = (_Float16)sspf(c0[q] + q2a);
      T[g * 4 + q][16 + r] = (_Float16)sspf(c1[q] + q2b);
      T[g * 4 + q][32 + r] = (_Float16)sspf(c2[q] + q2c);
      T[g * 4 + q][48 + r] = (_Float16)sspf(c3[q] + q2d);
    }
    const f16x8 t0 = *(const f16x8*)&T[r][g * 8];
    const f16x8 t1 = *(const f16x8*)&T[r][32 + g * 8];
    MFMA8(B3, t0, t1, c0, c1, c2, c3)
    const int nb = t * 16 + (g << 2);
#pragma unroll
    for (int q = 0; q < 4; ++q) {
      const int nq = nb + q;
      if (nq < n) {
        const size_t idx = ((size_t)nq << 6) + r;
        float n0 = h[idx +  0] + c0[q] + q3a;
        float n1 = h[idx + 16] + c1[q] + q3b;
        float n2 = h[idx + 32] + c2[q] + q3c;
        float n3 = h[idx + 48] + c3[q] + q3d;
        h[idx +  0] = n0; h16[idx +  0] = __float2half(n0);
        h[idx + 16] = n1; h16[idx + 16] = __float2half(n1);
        h[idx + 32] = n2; h16[idx + 32] = __float2half(n2);
        h[idx + 48] = n3; h16[idx + 48] = __float2half(n3);
      }
    }
  }
}

// Fused update + next-layer lin: t=ssp(agg@W2+b2); h+=t@W3+b3; x=fp16(h@C1next).
__global__ __launch_bounds__(256, 2) void upd1_k(
    const __half* __restrict__ aggh, const __half* __restrict__ wpk2,
    const float* __restrict__ b2, const __half* __restrict__ wpk3,
    const float* __restrict__ b3, float* __restrict__ h,
    __half* __restrict__ h16, const __half* __restrict__ wpkC,
    __half* __restrict__ x, int ntiles, int n) {
  __shared__ _Float16 lt[4][16][72];
  GEMM_PRO
  const int wslot = threadIdx.x >> 6;
  _Float16 (*T)[72] = lt[wslot];
  LOADB_P(B2, wpk2)
  LOADB_P(B3, wpk3)
  LOADB_P(BC, wpkC)
  const float q2a = b2[r], q2b = b2[16 + r], q2c = b2[32 + r], q2d = b2[48 + r];
  const float q3a = b3[r], q3b = b3[16 + r], q3c = b3[32 + r], q3d = b3[48 + r];
  for (int t = wid; t < ntiles; t += nwv) {
    int arow = t * 16 + r; if (arow >= n) arow = n - 1;
    const f16x8* Ap = (const f16x8*)(aggh + ((size_t)arow << 6));
    const f16x8 a0 = Ap[g], a1 = Ap[4 + g];
    f32x4 c0, c1, c2, c3;
    MFMA8(B2, a0, a1, c0, c1, c2, c3)
#pragma unroll
    for (int q = 0; q < 4; ++q) {
      T[g * 4 + q][r]      = (_Float16)sspf(c0[q] + q2a);
      T[g * 4 + q][16 + r] = (_Float16)sspf(c1[q] + q2b);
      T[g * 4 + q][32 + r] = (_Float16)sspf(c2[q] + q2c);
      T[g * 4 + q][48 + r] = (_Float16)sspf(c3[q] + q2d);
    }
    const f16x8 t0 = *(const f16x8*)&T[r][g * 8];
    const f16x8 t1 = *(const f16x8*)&T[r][32 + g * 8];
    MFMA8(B3, t0, t1, c0, c1, c2, c3)
    const int nb = t * 16 + (g << 2);
#pragma unroll
    for (int q = 0; q < 4; ++q) {
      const int nq = nb + q;
      float n0 = 0.f, n1 = 0.f, n2 = 0.f, n3 = 0.f;
      if (nq < n) {
        const size_t idx = ((size_t)nq << 6) + r;
        n0 = h[idx +  0] + c0[q] + q3a;
        n1 = h[idx + 16] + c1[q] + q3b;
        n2 = h[idx + 32] + c2[q] + q3c;
        n3 = h[idx + 48] + c3[q] + q3d;
        h[idx +  0] = n0; h16[idx +  0] = __float2half(n0);
        h[idx + 16] = n1; h16[idx + 16] = __float2half(n1);
        h[idx + 32] = n2; h16[idx + 32] = __float2half(n2);
        h[idx + 48] = n3; h16[idx + 48] = __float2half(n3);
      }
      T[g * 4 + q][r]      = (_Float16)n0;
      T[g * 4 + q][16 + r] = (_Float16)n1;
      T[g * 4 + q][32 + r] = (_Float16)n2;
      T[g * 4 + q][48 + r] = (_Float16)n3;
    }
    const f16x8 h0 = *(const f16x8*)&T[r][g * 8];
    const f16x8 h1 = *(const f16x8*)&T[r][32 + g * 8];
    MFMA8(BC, h0, h1, c0, c1, c2, c3)
#pragma unroll
    for (int q = 0; q < 4; ++q) {
      const int nq = nb + q;
      if (nq < n) {
        __half* o = x + ((size_t)nq << 6) + r;
        o[0]  = __float2half(c0[q]);
        o[16] = __float2half(c1[q]);
        o[32] = __float2half(c2[q]);
        o[48] = __float2half(c3[q]);
      }
    }
  }
}

// molecule output: o = h16 @ ow1 (64->32, 4 MFMAs); per-node
// s = sum_m ssp(o_m+b1_m)*ow2_m + b2 via 16-lane shfl_xor reduce; one atomic.
__global__ __launch_bounds__(256, 4) void outm16_k(
    const __half* __restrict__ h16, const int* __restrict__ batch,
    const __half* __restrict__ wpk, const float* __restrict__ ob1,
    const float* __restrict__ ow2, const float* __restrict__ ob2,
    float* __restrict__ outg, int ntiles, int n) {
  GEMM_PRO
  const f16x8* Bp = (const f16x8*)(wpk);
  const f16x8 b00 = Bp[0 * 64 + lane], b01 = Bp[1 * 64 + lane];
  const f16x8 b10 = Bp[2 * 64 + lane], b11 = Bp[3 * 64 + lane];
  const float b1a = ob1[r], b1b = ob1[16 + r];
  const float w2a = ow2[r], w2b = ow2[16 + r];
  const float b2o = ob2[0];
  for (int t = wid; t < ntiles; t += nwv) {
    int arow = t * 16 + r; if (arow >= n) arow = n - 1;
    const f16x8* Ap = (const f16x8*)(h16 + ((size_t)arow << 6));
    const f16x8 a0 = Ap[g], a1 = Ap[4 + g];
    f32x4 c0 = MFMA16(a0, b00, z4); c0 = MFMA16(a1, b01, c0);
    f32x4 c1 = MFMA16(a0, b10, z4); c1 = MFMA16(a1, b11, c1);
    float v0 = sspf(c0[0] + b1a) * w2a + sspf(c1[0] + b1b) * w2b;
    float v1 = sspf(c0[1] + b1a) * w2a + sspf(c1[1] + b1b) * w2b;
    float v2 = sspf(c0[2] + b1a) * w2a + sspf(c1[2] + b1b) * w2b;
    float v3 = sspf(c0[3] + b1a) * w2a + sspf(c1[3] + b1b) * w2b;
#pragma unroll
    for (int off = 1; off < 16; off <<= 1) {
      v0 += __shfl_xor(v0, off);
      v1 += __shfl_xor(v1, off);
      v2 += __shfl_xor(v2, off);
      v3 += __shfl_xor(v3, off);
    }
    if (r == 0) {
      const int nb = t * 16 + (g << 2);
      if (nb + 0 < n) unsafeAtomicAdd(&outg[batch[nb + 0]], v0 + b2o);
      if (nb + 1 < n) unsafeAtomicAdd(&outg[batch[nb + 1]], v1 + b2o);
      if (nb + 2 < n) unsafeAtomicAdd(&outg[batch[nb + 2]], v2 + b2o);
      if (nb + 3 < n) unsafeAtomicAdd(&outg[batch[nb + 3]], v3 + b2o);
    }
  }
}

// THE HOT KERNEL. One wave per dst node; R13: REVERT the R12 slot layout
// (fewer in-flight loads made the latency-bound kernel 29% slower) and push
// MLP up instead: 16-edge unroll = 32 row loads + 16 record loads in flight
// (was 16+8). fp16 agg out.
__global__ __launch_bounds__(256) void gather_k(
    const int* __restrict__ rs, const int* __restrict__ er,
    const __half* __restrict__ tabh, const __half* __restrict__ x,
    __half* __restrict__ aggh, int n) {
  int j = threadIdx.x & 63;
  int node = (blockIdx.x * 256 + threadIdx.x) >> 6;
  if (node >= n) return;
  int beg = __builtin_amdgcn_readfirstlane(rs[node]);
  int end = __builtin_amdgcn_readfirstlane(rs[node + 1]);
  float acc = 0.0f;
  int k = beg;
  for (; k + 16 <= end; k += 16) {
    int r0 = er[k + 0];
    int r1 = er[k + 1];
    int r2 = er[k + 2];
    int r3 = er[k + 3];
    int r4 = er[k + 4];
    int r5 = er[k + 5];
    int r6 = er[k + 6];
    int r7 = er[k + 7];
    int r8 = er[k + 8];
    int r9 = er[k + 9];
    int rA = er[k + 10];
    int rB = er[k + 11];
    int rC = er[k + 12];
    int rD = er[k + 13];
    int rE = er[k + 14];
    int rF = er[k + 15];
    float t0 = __half2float(tabh[(((size_t)((unsigned)r0 >> 17)) << 6) + j]);
    float t1 = __half2float(tabh[(((size_t)((unsigned)r1 >> 17)) << 6) + j]);
    float t2 = __half2float(tabh[(((size_t)((unsigned)r2 >> 17)) << 6) + j]);
    float t3 = __half2float(tabh[(((size_t)((unsigned)r3 >> 17)) << 6) + j]);
    float t4 = __half2float(tabh[(((size_t)((unsigned)r4 >> 17)) << 6) + j]);
    float t5 = __half2float(tabh[(((size_t)((unsigned)r5 >> 17)) << 6) + j]);
    float t6 = __half2float(tabh[(((size_t)((unsigned)r6 >> 17)) << 6) + j]);
    float t7 = __half2float(tabh[(((size_t)((unsigned)r7 >> 17)) << 6) + j]);
    float t8 = __half2float(tabh[(((size_t)((unsigned)r8 >> 17)) << 6) + j]);
    float t9 = __half2float(tabh[(((size_t)((unsigned)r9 >> 17)) << 6) + j]);
    float tA = __half2float(tabh[(((size_t)((unsigned)rA >> 17)) << 6) + j]);
    float tB = __half2float(tabh[(((size_t)((unsigned)rB >> 17)) << 6) + j]);
    float tC = __half2float(tabh[(((size_t)((unsigned)rC >> 17)) << 6) + j]);
    float tD = __half2float(tabh[(((size_t)((unsigned)rD >> 17)) << 6) + j]);
    float tE = __half2float(tabh[(((size_t)((unsigned)rE >> 17)) << 6) + j]);
    float tF = __half2float(tabh[(((size_t)((unsigned)rF >> 17)) << 6) + j]);
    float x0 = __half2float(x[((size_t)(r0 & 0x1FFFF) << 6) + j]);
    float x1 = __half2float(x[((size_t)(r1 & 0x1FFFF) << 6) + j]);
    float x2 = __half2float(x[((size_t)(r2 & 0x1FFFF) << 6) + j]);
    float x3 = __half2float(x[((size_t)(r3 & 0x1FFFF) << 6) + j]);
    float x4 = __half2float(x[((size_t)(r4 & 0x1FFFF) << 6) + j]);
    float x5 = __half2float(x[((size_t)(r5 & 0x1FFFF) << 6) + j]);
    float x6 = __half2float(x[((size_t)(r6 & 0x1FFFF) << 6) + j]);
    float x7 = __half2float(x[((size_t)(r7 & 0x1FFFF) << 6) + j]);
    float x8 = __half2float(x[((size_t)(r8 & 0x1FFFF) << 6) + j]);
    float x9 = __half2float(x[((size_t)(r9 & 0x1FFFF) << 6) + j]);
    float xA = __half2float(x[((size_t)(rA & 0x1FFFF) << 6) + j]);
    float xB = __half2float(x[((size_t)(rB & 0x1FFFF) << 6) + j]);
    float xC = __half2float(x[((size_t)(rC & 0x1FFFF) << 6) + j]);
    float xD = __half2float(x[((size_t)(rD & 0x1FFFF) << 6) + j]);
    float xE = __half2float(x[((size_t)(rE & 0x1FFFF) << 6) + j]);
    float xF = __half2float(x[((size_t)(rF & 0x1FFFF) << 6) + j]);
    acc = fmaf(x0, t0, acc);
    acc = fmaf(x1, t1, acc);
    acc = fmaf(x2, t2, acc);
    acc = fmaf(x3, t3, acc);
    acc = fmaf(x4, t4, acc);
    acc = fmaf(x5, t5, acc);
    acc = fmaf(x6, t6, acc);
    acc = fmaf(x7, t7, acc);
    acc = fmaf(x8, t8, acc);
    acc = fmaf(x9, t9, acc);
    acc = fmaf(xA, tA, acc);
    acc = fmaf(xB, tB, acc);
    acc = fmaf(xC, tC, acc);
    acc = fmaf(xD, tD, acc);
    acc = fmaf(xE, tE, acc);
    acc = fmaf(xF, tF, acc);
  }
  for (; k + 4 <= end; k += 4) {
    int r0 = er[k + 0];
    int r1 = er[k + 1];
    int r2 = er[k + 2];
    int r3 = er[k + 3];
    float t0 = __half2float(tabh[(((size_t)((unsigned)r0 >> 17)) << 6) + j]);
    float t1 = __half2float(tabh[(((size_t)((unsigned)r1 >> 17)) << 6) + j]);
    float t2 = __half2float(tabh[(((size_t)((unsigned)r2 >> 17)) << 6) + j]);
    float t3 = __half2float(tabh[(((size_t)((unsigned)r3 >> 17)) << 6) + j]);
    float x0 = __half2float(x[((size_t)(r0 & 0x1FFFF) << 6) + j]);
    float x1 = __half2float(x[((size_t)(r1 & 0x1FFFF) << 6) + j]);
    float x2 = __half2float(x[((size_t)(r2 & 0x1FFFF) << 6) + j]);
    float x3 = __half2float(x[((size_t)(r3 & 0x1FFFF) << 6) + j]);
    acc = fmaf(x0, t0, acc);
    acc = fmaf(x1, t1, acc);
    acc = fmaf(x2, t2, acc);
    acc = fmaf(x3, t3, acc);
  }
  for (; k < end; ++k) {
    int r = er[k];
    float t = __half2float(tabh[(((size_t)((unsigned)r >> 17)) << 6) + j]);
    float xv = __half2float(x[((size_t)(r & 0x1FFFF) << 6) + j]);
    acc = fmaf(xv, t, acc);
  }
  aggh[((size_t)node << 6) + j] = __float2half(acc);
}

__global__ __launch_bounds__(256) void final_k(
    const float* __restrict__ outg, const float* __restrict__ fw,
    const float* __restrict__ fb, float* __restrict__ out, int g) {
  int i = blockIdx.x * blockDim.x + threadIdx.x;
  if (i < g) out[i] = fmaf(outg[i], fw[0], fb[0]);
}

extern "C" void kernel_launch(void* const* d_in, const int* in_sizes, int n_in,
                              void* d_out, int out_size, void* d_ws, size_t ws_size,
                              hipStream_t stream) {
  const int*   z      = (const int*)d_in[0];
  const float* pos    = (const float*)d_in[1];
  const int*   batch  = (const int*)d_in[2];
  const int*   ei     = (const int*)d_in[3];
  const float* emb    = (const float*)d_in[4];
  const float* out_w1 = (const float*)d_in[5];
  const float* out_b1 = (const float*)d_in[6];
  const float* out_w2 = (const float*)d_in[7];
  const float* out_b2 = (const float*)d_in[8];
  const float* fin_w  = (const float*)d_in[9];
  const float* fin_b  = (const float*)d_in[10];
  const float* mlp_w1 = (const float*)d_in[11];
  const float* mlp_b1 = (const float*)d_in[12];
  const float* mlp_w2 = (const float*)d_in[13];
  const float* mlp_b2 = (const float*)d_in[14];
  const float* cf1    = (const float*)d_in[15];
  const float* cf2    = (const float*)d_in[16];
  const float* cf2b   = (const float*)d_in[17];
  const float* intw   = (const float*)d_in[18];
  const float* intb   = (const float*)d_in[19];

  const int N = in_sizes[0];
  const int E = in_sizes[3] / 2;
  const int G = out_size;
  const int NBUCK = (N + BSTRIDE - 1) / BSTRIDE;
  const int NCHUNK = (E + CHUNK_E - 1) / CHUNK_E;
  const int NTILES = (N + 15) / 16;
  const int GB = (NTILES + 3) / 4;     // 4 waves/block, 1 tile/wave

  char* wsb = (char*)d_ws;
  size_t off = 0;
  auto alloc = [&](size_t bytes) { char* p = wsb + off; off += (bytes + 255) & ~(size_t)255; return p; };
  float*   h     = (float*)alloc((size_t)N * HIDC * sizeof(float));
  __half*  h16   = (__half*)alloc((size_t)N * HIDC * sizeof(__half));
  __half*  x     = (__half*)alloc((size_t)N * HIDC * sizeof(__half));
  __half*  aggh  = (__half*)alloc((size_t)N * HIDC * sizeof(__half));
  __half*  tabh  = (__half*)alloc((size_t)NLAYER * TGRID * HIDC * sizeof(__half));
  __half*  wpk   = (__half*)alloc((size_t)10 * 4096 * sizeof(__half));
  int2*    er    = (int2*)alloc((size_t)E * sizeof(int2));   // bucket-ordered
  int*     er2   = (int*)alloc((size_t)E * sizeof(int));     // node-CSR, 4B packed
  int*     rs    = (int*)alloc((size_t)(N + 1) * sizeof(int));
  int*     bcnt  = (int*)alloc((size_t)MAXBUCK * sizeof(int));
  int*     boff  = (int*)alloc((size_t)MAXBUCK * sizeof(int));
  int*     chist = (int*)alloc((size_t)NCHUNK * MAXBUCK * sizeof(int));
  int*     cbase = (int*)alloc((size_t)NCHUNK * MAXBUCK * sizeof(int));
  float*   outg  = (float*)alloc((size_t)G * sizeof(float));

  build_table_k<<<dim3(NLAYER * TGRID), dim3(64), 0, stream>>>(
      mlp_w1, mlp_b1, mlp_w2, mlp_b2, tabh);
  pack_all_k<<<dim3(10), dim3(64), 0, stream>>>(cf1, cf2, intw, out_w1, wpk);
  (void)hipMemsetAsync(outg, 0, (size_t)G * sizeof(float), stream);
  (void)hipMemsetAsync(bcnt, 0, (size_t)MAXBUCK * sizeof(int), stream);
  chist_k<<<dim3(NCHUNK), dim3(256), 0, stream>>>(ei + E, chist, bcnt, E, NBUCK);
  bscan_k<<<dim3(1), dim3(256), 0, stream>>>(bcnt, boff, NBUCK);
  cbase_k<<<dim3(NBUCK), dim3(256), 0, stream>>>(chist, boff, cbase, NCHUNK);
  cstage_k<<<dim3(NCHUNK), dim3(512), 0, stream>>>(
      ei, pos, chist, cbase, er, E, NBUCK);
  bsort_k<<<dim3(NBUCK), dim3(256), 0, stream>>>(boff, bcnt, er, er2, rs, N);
  init_lin_k<<<dim3(GB), dim3(256), 0, stream>>>(
      z, emb, wpk, h, h16, x, NTILES, N);

  const int gather_blocks = (N + 3) / 4;   // one wave per node
  for (int l = 0; l < NLAYER; ++l) {
    gather_k<<<dim3(gather_blocks), dim3(256), 0, stream>>>(
        rs, er2, tabh + (size_t)l * TGRID * HIDC, x, aggh, N);
    if (l < NLAYER - 1) {
      upd1_k<<<dim3(GB), dim3(256), 0, stream>>>(
          aggh, wpk + (size_t)(3 + l) * 4096, cf2b + l * HIDC,
          wpk + (size_t)(6 + l) * 4096, intb + l * HIDC, h, h16,
          wpk + (size_t)(l + 1) * 4096, x, NTILES, N);
    } else {
      upd0_k<<<dim3(GB), dim3(256), 0, stream>>>(
          aggh, wpk + (size_t)(3 + l) * 4096, cf2b + l * HIDC,
          wpk + (size_t)(6 + l) * 4096, intb + l * HIDC, h, h16, NTILES, N);
    }
  }

  outm16_k<<<dim3(GB), dim3(256), 0, stream>>>(
      h16, batch, wpk + (size_t)9 * 4096, out_b1, out_w2, out_b2, outg, NTILES, N);
  final_k<<<dim3((G + 255) / 256), dim3(256), 0, stream>>>(
      outg, fin_w, fin_b, (float*)d_out, G);
}